// Round 18
// baseline (61.880 us; speedup 1.0000x reference)
//
#include <hip/hip_runtime.h>
#include <hip/hip_fp16.h>
#include <math.h>

#define NN    320
#define CC    16
#define PP    262144
#define OSZ   360
#define HOSZ  180
#define BETA2 19.519727f
#define PIW_OS 0.02617993878f                 // pi*W/OS = pi/120
#define RAD_PER 0.017453292519943295f         // 2*pi/360
#define TBL_OFF (6u * 1024u * 1024u)          // tables at d_ws + 6MB

// bf16 round-to-nearest-even (result in low 16 bits)
__device__ __forceinline__ unsigned int f2bf(float f) {
  unsigned int u = __float_as_uint(f);
  return (u + 0x7FFFu + ((u >> 16) & 1u)) >> 16;
}

// Kaiser-Bessel weight: degree-12 Horner in arg = 1-(2d/3)^2 (exact Taylor
// of I0(beta*sqrt(arg)); tail 2e-11). d in [-1.5,1.5] -> branchless.
__device__ __forceinline__ float kbw(float d) {
  float xf = 0.66666667f * d;
  float h = fmaxf(fmaf(-xf, xf, 1.0f), 0.0f);
  float w =            7.948604e-10f;
  w = fmaf(w, h, 2.345522e-8f);
  w = fmaf(w, h, 5.815822e-7f);
  w = fmaf(w, h, 1.191783e-5f);
  w = fmaf(w, h, 1.978192e-4f);
  w = fmaf(w, h, 2.594386e-3f);
  w = fmaf(w, h, 2.605055e-2f);
  w = fmaf(w, h, 1.921789e-1f);
  w = fmaf(w, h, 9.845368e-1f);
  w = fmaf(w, h, 3.228036f);
  w = fmaf(w, h, 5.953434f);
  w = fmaf(w, h, 4.8799318f);
  w = fmaf(w, h, 1.0f);
  return w;
}

// Sentinel: fill first 64 output floats with a marker value (diagnostic).
__global__ void sentinel_kernel(float* out, float v) {
  if (threadIdx.x < 64) out[threadIdx.x] = v;
}

// One-shot table kernel: tw[360] float2, apod[320] float (L2-resident after).
__global__ void init_tables(float2* __restrict__ twg, float* __restrict__ apodg) {
  int t = threadIdx.x;
  if (t < OSZ) {
    float sn, cs; sincosf(-RAD_PER * (float)t, &sn, &cs);
    twg[t] = make_float2(cs, sn);
  }
  if (t < NN) {
    float u = PIW_OS * (float)(t - 160);
    float t2 = BETA2 - u * u;
    float s = sqrtf(fmaxf(t2, 1e-12f));
    apodg[t] = s / sinhf(s);
  }
}

// ---------------------------------------------------------------------------
// Two-stage Cooley-Tukey 360 = 18 x 20, k/k+180 parity-paired, QT=2 rows per
// block, 192 threads, 2880 blocks/pass. Tables loaded from global (no
// per-block transcendentals).
// ---------------------------------------------------------------------------

// Pass 1: block = (c, 2-row q-tile). T1h[c][k][q] = one __half2 per complex.
__global__ __launch_bounds__(192) void nufft_pass1(
    const float* __restrict__ imr, const float* __restrict__ imi,
    const float2* __restrict__ twg, const float* __restrict__ apodg,
    __half2* __restrict__ T1h) {
  int bid = blockIdx.x;
  int c  = bid / 180;                        // 180 tiles per channel
  int qt = bid - c * 180;
  int q0 = qt * 2;
  int tid = threadIdx.x;

  __shared__ float2 tw[OSZ];
  __shared__ float  apodL[NN];
  __shared__ float2 srow[2][OSZ];
  __shared__ float2 A[2][18 * 21];

  for (int n = tid; n < OSZ; n += 192) tw[n] = twg[n];
  for (int i = tid; i < NN; i += 192) apodL[i] = apodg[i];

  // fully-zero q-tile fast path (q in [160,200) are pad rows; boundaries
  // 160/200 are even so no tile straddles)
  if (q0 >= 160 && q0 < 200) {
    if (tid < OSZ)
      *(uint2*)&T1h[((size_t)(c * OSZ + tid)) * OSZ + q0] = make_uint2(0u, 0u);
    return;
  }
  __syncthreads();                            // apodL ready

  const float inv360 = 1.0f / 360.0f;
  for (int i = tid; i < 2 * OSZ; i += 192) {
    int r = i / OSZ, n = i - r * OSZ;
    int q = q0 + r;
    int y = (q + 180) % OSZ - 20;
    int x = (n + 180) % OSZ - 20;
    float2 v = make_float2(0.0f, 0.0f);
    if (y >= 0 && y < NN && x >= 0 && x < NN) {
      float s = apodL[x] * (apodL[y] * inv360);
      size_t o = (size_t)(c * NN + y) * NN + x;
      v = make_float2(imr[o] * s, imi[o] * s);
    }
    srow[r][n] = v;
  }
  __syncthreads();

  if (tid < 180) {                            // stage 1: k1 / k1+9 paired
    int k1 = tid / 20, n2 = tid - k1 * 20;    // k1 in 0..8
    int dm = 20 * k1;
    float arA[2], aiA[2], arB[2], aiB[2];
    #pragma unroll
    for (int r = 0; r < 2; ++r) { arA[r]=0.f; aiA[r]=0.f; arB[r]=0.f; aiB[r]=0.f; }
    int m = 0, idx = n2;
    #pragma unroll
    for (int n1 = 0; n1 < 18; ++n1) {
      if (n1 != 8 && n1 != 9) {               // pad band: exact zeros
        float2 w = tw[m];
        float sx = (n1 & 1) ? -w.x : w.x;     // (-1)^{n1} tw == tw for k1+9
        float sy = (n1 & 1) ? -w.y : w.y;
        #pragma unroll
        for (int r = 0; r < 2; ++r) {
          float2 v = srow[r][idx];
          arA[r] = fmaf(v.x, w.x, arA[r]); arA[r] = fmaf(-v.y, w.y, arA[r]);
          aiA[r] = fmaf(v.x, w.y, aiA[r]); aiA[r] = fmaf( v.y, w.x, aiA[r]);
          arB[r] = fmaf(v.x, sx,  arB[r]); arB[r] = fmaf(-v.y, sy,  arB[r]);
          aiB[r] = fmaf(v.x, sy,  aiB[r]); aiB[r] = fmaf( v.y, sx,  aiB[r]);
        }
      }
      idx += 20; m += dm; if (m >= OSZ) m -= OSZ;
    }
    #pragma unroll
    for (int r = 0; r < 2; ++r) {
      A[r][k1 * 21 + n2]       = make_float2(arA[r], aiA[r]);
      A[r][(k1 + 9) * 21 + n2] = make_float2(arB[r], aiB[r]);
    }
  }
  __syncthreads();

  if (tid < 180) {                            // stage 2: k / k+180 paired
    int k = tid;
    int base = (k % 18) * 21;                 // shared by k and k+180
    float2 step = tw[k];
    float wr = 1.0f, wi = 0.0f;
    float xrA[2], xiA[2], xrB[2], xiB[2];
    #pragma unroll
    for (int r = 0; r < 2; ++r) { xrA[r]=0.f; xiA[r]=0.f; xrB[r]=0.f; xiB[r]=0.f; }
    #pragma unroll
    for (int n2 = 0; n2 < 20; ++n2) {
      float sbr = (n2 & 1) ? -wr : wr;        // (-1)^{n2} w == twiddle of k+180
      float sbi = (n2 & 1) ? -wi : wi;
      #pragma unroll
      for (int r = 0; r < 2; ++r) {
        float2 a = A[r][base + n2];
        xrA[r] = fmaf(a.x, wr,  xrA[r]); xrA[r] = fmaf(-a.y, wi,  xrA[r]);
        xiA[r] = fmaf(a.x, wi,  xiA[r]); xiA[r] = fmaf( a.y, wr,  xiA[r]);
        xrB[r] = fmaf(a.x, sbr, xrB[r]); xrB[r] = fmaf(-a.y, sbi, xrB[r]);
        xiB[r] = fmaf(a.x, sbi, xiB[r]); xiB[r] = fmaf( a.y, sbr, xiB[r]);
      }
      float nwr = fmaf(wr, step.x, -wi * step.y);
      float nwi = fmaf(wr, step.y,  wi * step.x);
      wr = nwr; wi = nwi;
    }
    __half2 a0 = __float22half2_rn(make_float2(xrA[0], xiA[0]));
    __half2 a1 = __float22half2_rn(make_float2(xrA[1], xiA[1]));
    *(uint2*)&T1h[((size_t)(c * OSZ + k)) * OSZ + q0] =
        make_uint2(*(unsigned int*)&a0, *(unsigned int*)&a1);
    __half2 b0 = __float22half2_rn(make_float2(xrB[0], xiB[0]));
    __half2 b1 = __float22half2_rn(make_float2(xrB[1], xiB[1]));
    *(uint2*)&T1h[((size_t)(c * OSZ + k + HOSZ)) * OSZ + q0] =
        make_uint2(*(unsigned int*)&b0, *(unsigned int*)&b1);
  }
}

// Pass 2: block = (kx, 2-channel group), 2880 blocks. Parity-paired stages.
// Writes KGb (bf16, pre-fftshifted): KGb[(k+180)%360][(kx+180)%360][c].
__global__ __launch_bounds__(192) void nufft_pass2(
    const __half2* __restrict__ T1h, const float2* __restrict__ twg,
    unsigned short* __restrict__ KGb) {
  int bid = blockIdx.x;
  int kx  = bid >> 3;
  int ch0 = (bid & 7) * 2;
  int tid = threadIdx.x;

  __shared__ float2 tw[OSZ];
  __shared__ float2 srow[2][OSZ];
  __shared__ float2 A[2][18 * 21];

  for (int n = tid; n < OSZ; n += 192) tw[n] = twg[n];
  // load 2 channels' q-columns (T1 rows zero for q in [160,200): skip read)
  for (int i = tid; i < 2 * OSZ; i += 192) {
    int ci = i / OSZ, n = i - ci * OSZ;
    float2 v = make_float2(0.0f, 0.0f);
    if (n < 160 || n >= 200)
      v = __half22float2(T1h[((size_t)((ch0 + ci) * OSZ + kx)) * OSZ + n]);
    srow[ci][n] = v;
  }
  __syncthreads();

  if (tid < 180) {                            // stage 1: k1 / k1+9 paired
    int k1 = tid / 20, n2 = tid - k1 * 20;
    int dm = 20 * k1;
    float arA[2], aiA[2], arB[2], aiB[2];
    #pragma unroll
    for (int r = 0; r < 2; ++r) { arA[r]=0.f; aiA[r]=0.f; arB[r]=0.f; aiB[r]=0.f; }
    int m = 0, idx = n2;
    #pragma unroll
    for (int n1 = 0; n1 < 18; ++n1) {
      if (n1 != 8 && n1 != 9) {               // q pad band, exact zeros
        float2 w = tw[m];
        float sx = (n1 & 1) ? -w.x : w.x;
        float sy = (n1 & 1) ? -w.y : w.y;
        #pragma unroll
        for (int r = 0; r < 2; ++r) {
          float2 v = srow[r][idx];
          arA[r] = fmaf(v.x, w.x, arA[r]); arA[r] = fmaf(-v.y, w.y, arA[r]);
          aiA[r] = fmaf(v.x, w.y, aiA[r]); aiA[r] = fmaf( v.y, w.x, aiA[r]);
          arB[r] = fmaf(v.x, sx,  arB[r]); arB[r] = fmaf(-v.y, sy,  arB[r]);
          aiB[r] = fmaf(v.x, sy,  aiB[r]); aiB[r] = fmaf( v.y, sx,  aiB[r]);
        }
      }
      idx += 20; m += dm; if (m >= OSZ) m -= OSZ;
    }
    #pragma unroll
    for (int r = 0; r < 2; ++r) {
      A[r][k1 * 21 + n2]       = make_float2(arA[r], aiA[r]);
      A[r][(k1 + 9) * 21 + n2] = make_float2(arB[r], aiB[r]);
    }
  }
  __syncthreads();

  if (tid < 180) {                            // stage 2: k / k+180, Re only
    int k = tid;
    int base = (k % 18) * 21;
    float2 step = tw[k];
    float wr = 1.0f, wi = 0.0f;
    float xrA[2], xrB[2];
    #pragma unroll
    for (int r = 0; r < 2; ++r) { xrA[r] = 0.f; xrB[r] = 0.f; }
    #pragma unroll
    for (int n2 = 0; n2 < 20; ++n2) {
      float sbr = (n2 & 1) ? -wr : wr;
      float sbi = (n2 & 1) ? -wi : wi;
      #pragma unroll
      for (int r = 0; r < 2; ++r) {
        float2 a = A[r][base + n2];
        xrA[r] = fmaf(a.x, wr,  xrA[r]); xrA[r] = fmaf(-a.y, wi,  xrA[r]);
        xrB[r] = fmaf(a.x, sbr, xrB[r]); xrB[r] = fmaf(-a.y, sbi, xrB[r]);
      }
      float nwr = fmaf(wr, step.x, -wi * step.y);
      float nwi = fmaf(wr, step.y,  wi * step.x);
      wr = nwr; wi = nwi;
    }
    int colS = kx + HOSZ; if (colS >= OSZ) colS -= OSZ;
    // k = tid -> shifted row tid+180 ; k+180 -> shifted row tid
    unsigned int pkA = (f2bf(xrA[1]) << 16) | f2bf(xrA[0]);
    unsigned int pkB = (f2bf(xrB[1]) << 16) | f2bf(xrB[0]);
    *(unsigned int*)&KGb[((size_t)(tid + HOSZ) * OSZ + colS) * CC + ch0] = pkA;
    *(unsigned int*)&KGb[((size_t)tid * OSZ + colS) * CC + ch0]          = pkB;
  }
}

// ---------------------------------------------------------------------------
// Gridder v6: FOUR lanes per point (q = g&3); each lane loads one uint2
// (8B = 4 bf16 channels) per tap -> lanes 4i..4i+3 cover the 32B cell, no
// line amplification, 2x waves in flight vs v5. Polynomial KB weights.
// OUTPUT: float32 (C,P).
// ---------------------------------------------------------------------------
__global__ __launch_bounds__(256) void grid_points4(
    const float* __restrict__ coord, const unsigned short* __restrict__ KGb,
    float* __restrict__ out) {
  int g = blockIdx.x * 256 + threadIdx.x;     // g = p*4 + q
  int p = g >> 2;
  int q = g & 3;
  if (p >= PP) return;

  float2 cv = ((const float2*)coord)[p];
  float posy = __fadd_rn(__fmul_rn(cv.x, 1.125f), 180.0f);
  float posx = __fadd_rn(__fmul_rn(cv.y, 1.125f), 180.0f);
  float sty = ceilf(__fadd_rn(posy, -1.5f));
  float stx = ceilf(__fadd_rn(posx, -1.5f));

  float wy[3], wx[3];
  int jy[3], jx[3];
  #pragma unroll
  for (int r = 0; r < 3; ++r) {
    float gy = sty + (float)r;
    wy[r] = kbw(posy - gy);
    int gi = (int)gy;                          // gi in [-1,360]
    if (gi < 0) gi += OSZ;
    if (gi >= OSZ) gi -= OSZ;
    jy[r] = gi;

    float gx = stx + (float)r;
    wx[r] = kbw(posx - gx);
    gi = (int)gx;
    if (gi < 0) gi += OSZ;
    if (gi >= OSZ) gi -= OSZ;
    jx[r] = gi;
  }

  float acc[4];
  #pragma unroll
  for (int j = 0; j < 4; ++j) acc[j] = 0.0f;

  #pragma unroll
  for (int a = 0; a < 3; ++a) {
    #pragma unroll
    for (int b = 0; b < 3; ++b) {
      float w = wy[a] * wx[b];
      const uint2* cell = (const uint2*)(KGb + ((size_t)jy[a] * OSZ + jx[b]) * CC);
      uint2 v = cell[q];                      // 4 bf16 channels
      acc[0] = fmaf(w, __uint_as_float(v.x << 16),          acc[0]);
      acc[1] = fmaf(w, __uint_as_float(v.x & 0xffff0000u),  acc[1]);
      acc[2] = fmaf(w, __uint_as_float(v.y << 16),          acc[2]);
      acc[3] = fmaf(w, __uint_as_float(v.y & 0xffff0000u),  acc[3]);
    }
  }

  int c0 = q * 4;
  #pragma unroll
  for (int j = 0; j < 4; ++j) out[(size_t)(c0 + j) * PP + p] = acc[j];
}

extern "C" void kernel_launch(void* const* d_in, const int* in_sizes, int n_in,
                              void* d_out, int out_size, void* d_ws, size_t ws_size,
                              hipStream_t stream) {
  bool sizes_ok = (n_in >= 3) &&
                  (in_sizes[0] == CC * NN * NN) &&
                  (in_sizes[1] == CC * NN * NN) &&
                  (in_sizes[2] == PP * 2);
  if (!sizes_ok) {
    hipLaunchKernelGGL(sentinel_kernel, dim3(1), dim3(64), 0, stream,
                       (float*)d_out, 555.0f);
    return;
  }
  if (ws_size < TBL_OFF + OSZ * sizeof(float2) + NN * sizeof(float)) {
    hipLaunchKernelGGL(sentinel_kernel, dim3(1), dim3(64), 0, stream,
                       (float*)d_out, 777.0f);
    return;
  }

  const float* imr   = (const float*)d_in[0];
  const float* imi   = (const float*)d_in[1];
  const float* coord = (const float*)d_in[2];

  // d_out = 4,194,304 float32 = 16.78 MB (real part of kdata, (C,P)).
  // T1h scratch (complex fp16, 8.29 MB) fits in d_out, dead before
  // grid_points4 overwrites all of d_out. KGb (bf16, 4.15 MB) at d_ws;
  // tw/apod tables at d_ws + 6MB (ws >= 16.59 MB proven by r9-r13 sentinel).
  __half2* T1h = (__half2*)d_out;
  unsigned short* KGb = (unsigned short*)d_ws;
  float2* twg  = (float2*)((char*)d_ws + TBL_OFF);
  float*  apodg = (float*)(twg + OSZ);

  hipLaunchKernelGGL(init_tables, dim3(1), dim3(384), 0, stream, twg, apodg);
  hipLaunchKernelGGL(nufft_pass1, dim3(CC * 180), dim3(192), 0, stream,
                     imr, imi, twg, apodg, T1h);
  hipLaunchKernelGGL(nufft_pass2, dim3(OSZ * 8), dim3(192), 0, stream,
                     T1h, twg, KGb);
  hipLaunchKernelGGL(grid_points4, dim3((PP * 4) / 256), dim3(256), 0, stream,
                     coord, KGb, (float*)d_out);
}

// Round 19
// 58.132 us; speedup vs baseline: 1.0645x; 1.0645x over previous
//
#include <hip/hip_runtime.h>
#include <hip/hip_fp16.h>
#include <math.h>

#define NN    320
#define CC    16
#define PP    262144
#define OSZ   360
#define HOSZ  180
#define BETA2 19.519727f
#define PIW_OS 0.02617993878f                 // pi*W/OS = pi/120
#define RAD_PER 0.017453292519943295f         // 2*pi/360

// image-domain apodization a[i] via HW exp: t/sinh(t), t in [1.4,4.42]
__device__ __forceinline__ float apodf(int i) {
  float u = PIW_OS * (float)(i - 160);
  float t2 = fmaxf(BETA2 - u * u, 1e-12f);
  float t = sqrtf(t2);
  float ep = __expf(t), en = __expf(-t);
  return t / (0.5f * (ep - en));
}

// bf16 round-to-nearest-even (result in low 16 bits)
__device__ __forceinline__ unsigned int f2bf(float f) {
  unsigned int u = __float_as_uint(f);
  return (u + 0x7FFFu + ((u >> 16) & 1u)) >> 16;
}

// Kaiser-Bessel weight: degree-12 Horner in arg = 1-(2d/3)^2 (exact Taylor
// of I0(beta*sqrt(arg)); tail 2e-11). d in [-1.5,1.5] -> branchless.
__device__ __forceinline__ float kbw(float d) {
  float xf = 0.66666667f * d;
  float h = fmaxf(fmaf(-xf, xf, 1.0f), 0.0f);
  float w =            7.948604e-10f;
  w = fmaf(w, h, 2.345522e-8f);
  w = fmaf(w, h, 5.815822e-7f);
  w = fmaf(w, h, 1.191783e-5f);
  w = fmaf(w, h, 1.978192e-4f);
  w = fmaf(w, h, 2.594386e-3f);
  w = fmaf(w, h, 2.605055e-2f);
  w = fmaf(w, h, 1.921789e-1f);
  w = fmaf(w, h, 9.845368e-1f);
  w = fmaf(w, h, 3.228036f);
  w = fmaf(w, h, 5.953434f);
  w = fmaf(w, h, 4.8799318f);
  w = fmaf(w, h, 1.0f);
  return w;
}

// Sentinel: fill first 64 output floats with a marker value (diagnostic).
__global__ void sentinel_kernel(float* out, float v) {
  if (threadIdx.x < 64) out[threadIdx.x] = v;
}

// ---------------------------------------------------------------------------
// Two-stage Cooley-Tukey 360 = 18 x 20, k/k+180 parity-paired, QT=2 rows per
// block, 192 threads, 2880 blocks/pass (r17 structure; best known). Preamble
// trig/exp now uses HW instructions (v_sin/v_cos/v_exp) instead of libm.
// ---------------------------------------------------------------------------

// Pass 1: block = (c, 2-row q-tile). T1h[c][k][q] = one __half2 per complex.
__global__ __launch_bounds__(192) void nufft_pass1(
    const float* __restrict__ imr, const float* __restrict__ imi,
    __half2* __restrict__ T1h) {
  int bid = blockIdx.x;
  int c  = bid / 180;                        // 180 tiles per channel
  int qt = bid - c * 180;
  int q0 = qt * 2;
  int tid = threadIdx.x;

  __shared__ float2 tw[OSZ];
  __shared__ float  apodL[NN];
  __shared__ float2 srow[2][OSZ];
  __shared__ float2 A[2][18 * 21];

  for (int n = tid; n < OSZ; n += 192) {
    float a = -RAD_PER * (float)n;
    tw[n] = make_float2(__cosf(a), __sinf(a));   // HW trig
  }
  for (int i = tid; i < NN; i += 192) apodL[i] = apodf(i);

  // fully-zero q-tile fast path (q in [160,200) are pad rows; boundaries
  // 160/200 are even so no tile straddles)
  if (q0 >= 160 && q0 < 200) {
    if (tid < OSZ)
      *(uint2*)&T1h[((size_t)(c * OSZ + tid)) * OSZ + q0] = make_uint2(0u, 0u);
    return;
  }
  __syncthreads();                            // apodL ready

  const float inv360 = 1.0f / 360.0f;
  for (int i = tid; i < 2 * OSZ; i += 192) {
    int r = i / OSZ, n = i - r * OSZ;
    int q = q0 + r;
    int y = (q + 180) % OSZ - 20;
    int x = (n + 180) % OSZ - 20;
    float2 v = make_float2(0.0f, 0.0f);
    if (y >= 0 && y < NN && x >= 0 && x < NN) {
      float s = apodL[x] * (apodL[y] * inv360);
      size_t o = (size_t)(c * NN + y) * NN + x;
      v = make_float2(imr[o] * s, imi[o] * s);
    }
    srow[r][n] = v;
  }
  __syncthreads();

  if (tid < 180) {                            // stage 1: k1 / k1+9 paired
    int k1 = tid / 20, n2 = tid - k1 * 20;    // k1 in 0..8
    int dm = 20 * k1;
    float arA[2], aiA[2], arB[2], aiB[2];
    #pragma unroll
    for (int r = 0; r < 2; ++r) { arA[r]=0.f; aiA[r]=0.f; arB[r]=0.f; aiB[r]=0.f; }
    int m = 0, idx = n2;
    #pragma unroll
    for (int n1 = 0; n1 < 18; ++n1) {
      if (n1 != 8 && n1 != 9) {               // pad band: exact zeros
        float2 w = tw[m];
        float sx = (n1 & 1) ? -w.x : w.x;     // (-1)^{n1} tw == tw for k1+9
        float sy = (n1 & 1) ? -w.y : w.y;
        #pragma unroll
        for (int r = 0; r < 2; ++r) {
          float2 v = srow[r][idx];
          arA[r] = fmaf(v.x, w.x, arA[r]); arA[r] = fmaf(-v.y, w.y, arA[r]);
          aiA[r] = fmaf(v.x, w.y, aiA[r]); aiA[r] = fmaf( v.y, w.x, aiA[r]);
          arB[r] = fmaf(v.x, sx,  arB[r]); arB[r] = fmaf(-v.y, sy,  arB[r]);
          aiB[r] = fmaf(v.x, sy,  aiB[r]); aiB[r] = fmaf( v.y, sx,  aiB[r]);
        }
      }
      idx += 20; m += dm; if (m >= OSZ) m -= OSZ;
    }
    #pragma unroll
    for (int r = 0; r < 2; ++r) {
      A[r][k1 * 21 + n2]       = make_float2(arA[r], aiA[r]);
      A[r][(k1 + 9) * 21 + n2] = make_float2(arB[r], aiB[r]);
    }
  }
  __syncthreads();

  if (tid < 180) {                            // stage 2: k / k+180 paired
    int k = tid;
    int base = (k % 18) * 21;                 // shared by k and k+180
    float2 step = tw[k];
    float wr = 1.0f, wi = 0.0f;
    float xrA[2], xiA[2], xrB[2], xiB[2];
    #pragma unroll
    for (int r = 0; r < 2; ++r) { xrA[r]=0.f; xiA[r]=0.f; xrB[r]=0.f; xiB[r]=0.f; }
    #pragma unroll
    for (int n2 = 0; n2 < 20; ++n2) {
      float sbr = (n2 & 1) ? -wr : wr;        // (-1)^{n2} w == twiddle of k+180
      float sbi = (n2 & 1) ? -wi : wi;
      #pragma unroll
      for (int r = 0; r < 2; ++r) {
        float2 a = A[r][base + n2];
        xrA[r] = fmaf(a.x, wr,  xrA[r]); xrA[r] = fmaf(-a.y, wi,  xrA[r]);
        xiA[r] = fmaf(a.x, wi,  xiA[r]); xiA[r] = fmaf( a.y, wr,  xiA[r]);
        xrB[r] = fmaf(a.x, sbr, xrB[r]); xrB[r] = fmaf(-a.y, sbi, xrB[r]);
        xiB[r] = fmaf(a.x, sbi, xiB[r]); xiB[r] = fmaf( a.y, sbr, xiB[r]);
      }
      float nwr = fmaf(wr, step.x, -wi * step.y);
      float nwi = fmaf(wr, step.y,  wi * step.x);
      wr = nwr; wi = nwi;
    }
    __half2 a0 = __float22half2_rn(make_float2(xrA[0], xiA[0]));
    __half2 a1 = __float22half2_rn(make_float2(xrA[1], xiA[1]));
    *(uint2*)&T1h[((size_t)(c * OSZ + k)) * OSZ + q0] =
        make_uint2(*(unsigned int*)&a0, *(unsigned int*)&a1);
    __half2 b0 = __float22half2_rn(make_float2(xrB[0], xiB[0]));
    __half2 b1 = __float22half2_rn(make_float2(xrB[1], xiB[1]));
    *(uint2*)&T1h[((size_t)(c * OSZ + k + HOSZ)) * OSZ + q0] =
        make_uint2(*(unsigned int*)&b0, *(unsigned int*)&b1);
  }
}

// Pass 2: block = (kx, 2-channel group), 2880 blocks. Parity-paired stages.
// Writes KGb (bf16, pre-fftshifted): KGb[(k+180)%360][(kx+180)%360][c].
__global__ __launch_bounds__(192) void nufft_pass2(
    const __half2* __restrict__ T1h, unsigned short* __restrict__ KGb) {
  int bid = blockIdx.x;
  int kx  = bid >> 3;
  int ch0 = (bid & 7) * 2;
  int tid = threadIdx.x;

  __shared__ float2 tw[OSZ];
  __shared__ float2 srow[2][OSZ];
  __shared__ float2 A[2][18 * 21];

  for (int n = tid; n < OSZ; n += 192) {
    float a = -RAD_PER * (float)n;
    tw[n] = make_float2(__cosf(a), __sinf(a));   // HW trig
  }
  // load 2 channels' q-columns (T1 rows zero for q in [160,200): skip read)
  for (int i = tid; i < 2 * OSZ; i += 192) {
    int ci = i / OSZ, n = i - ci * OSZ;
    float2 v = make_float2(0.0f, 0.0f);
    if (n < 160 || n >= 200)
      v = __half22float2(T1h[((size_t)((ch0 + ci) * OSZ + kx)) * OSZ + n]);
    srow[ci][n] = v;
  }
  __syncthreads();

  if (tid < 180) {                            // stage 1: k1 / k1+9 paired
    int k1 = tid / 20, n2 = tid - k1 * 20;
    int dm = 20 * k1;
    float arA[2], aiA[2], arB[2], aiB[2];
    #pragma unroll
    for (int r = 0; r < 2; ++r) { arA[r]=0.f; aiA[r]=0.f; arB[r]=0.f; aiB[r]=0.f; }
    int m = 0, idx = n2;
    #pragma unroll
    for (int n1 = 0; n1 < 18; ++n1) {
      if (n1 != 8 && n1 != 9) {               // q pad band, exact zeros
        float2 w = tw[m];
        float sx = (n1 & 1) ? -w.x : w.x;
        float sy = (n1 & 1) ? -w.y : w.y;
        #pragma unroll
        for (int r = 0; r < 2; ++r) {
          float2 v = srow[r][idx];
          arA[r] = fmaf(v.x, w.x, arA[r]); arA[r] = fmaf(-v.y, w.y, arA[r]);
          aiA[r] = fmaf(v.x, w.y, aiA[r]); aiA[r] = fmaf( v.y, w.x, aiA[r]);
          arB[r] = fmaf(v.x, sx,  arB[r]); arB[r] = fmaf(-v.y, sy,  arB[r]);
          aiB[r] = fmaf(v.x, sy,  aiB[r]); aiB[r] = fmaf( v.y, sx,  aiB[r]);
        }
      }
      idx += 20; m += dm; if (m >= OSZ) m -= OSZ;
    }
    #pragma unroll
    for (int r = 0; r < 2; ++r) {
      A[r][k1 * 21 + n2]       = make_float2(arA[r], aiA[r]);
      A[r][(k1 + 9) * 21 + n2] = make_float2(arB[r], aiB[r]);
    }
  }
  __syncthreads();

  if (tid < 180) {                            // stage 2: k / k+180, Re only
    int k = tid;
    int base = (k % 18) * 21;
    float2 step = tw[k];
    float wr = 1.0f, wi = 0.0f;
    float xrA[2], xrB[2];
    #pragma unroll
    for (int r = 0; r < 2; ++r) { xrA[r] = 0.f; xrB[r] = 0.f; }
    #pragma unroll
    for (int n2 = 0; n2 < 20; ++n2) {
      float sbr = (n2 & 1) ? -wr : wr;
      float sbi = (n2 & 1) ? -wi : wi;
      #pragma unroll
      for (int r = 0; r < 2; ++r) {
        float2 a = A[r][base + n2];
        xrA[r] = fmaf(a.x, wr,  xrA[r]); xrA[r] = fmaf(-a.y, wi,  xrA[r]);
        xrB[r] = fmaf(a.x, sbr, xrB[r]); xrB[r] = fmaf(-a.y, sbi, xrB[r]);
      }
      float nwr = fmaf(wr, step.x, -wi * step.y);
      float nwi = fmaf(wr, step.y,  wi * step.x);
      wr = nwr; wi = nwi;
    }
    int colS = kx + HOSZ; if (colS >= OSZ) colS -= OSZ;
    // k = tid -> shifted row tid+180 ; k+180 -> shifted row tid
    unsigned int pkA = (f2bf(xrA[1]) << 16) | f2bf(xrA[0]);
    unsigned int pkB = (f2bf(xrB[1]) << 16) | f2bf(xrB[0]);
    *(unsigned int*)&KGb[((size_t)(tid + HOSZ) * OSZ + colS) * CC + ch0] = pkA;
    *(unsigned int*)&KGb[((size_t)tid * OSZ + colS) * CC + ch0]          = pkB;
  }
}

// ---------------------------------------------------------------------------
// Gridder v5 (r17, best known): two lanes per point; 16B (8 bf16 channels)
// per tap per lane; branchless polynomial KB weights. OUTPUT: float32 (C,P).
// ---------------------------------------------------------------------------
__global__ __launch_bounds__(256) void grid_points2(
    const float* __restrict__ coord, const unsigned short* __restrict__ KGb,
    float* __restrict__ out) {
  int g = blockIdx.x * 256 + threadIdx.x;     // g = p*2 + q
  int p = g >> 1;
  int q = g & 1;
  if (p >= PP) return;

  float2 cv = ((const float2*)coord)[p];
  float posy = __fadd_rn(__fmul_rn(cv.x, 1.125f), 180.0f);
  float posx = __fadd_rn(__fmul_rn(cv.y, 1.125f), 180.0f);
  float sty = ceilf(__fadd_rn(posy, -1.5f));
  float stx = ceilf(__fadd_rn(posx, -1.5f));

  float wy[3], wx[3];
  int jy[3], jx[3];
  #pragma unroll
  for (int r = 0; r < 3; ++r) {
    float gy = sty + (float)r;
    wy[r] = kbw(posy - gy);
    int gi = (int)gy;                          // gi in [-1,360]
    if (gi < 0) gi += OSZ;
    if (gi >= OSZ) gi -= OSZ;
    jy[r] = gi;

    float gx = stx + (float)r;
    wx[r] = kbw(posx - gx);
    gi = (int)gx;
    if (gi < 0) gi += OSZ;
    if (gi >= OSZ) gi -= OSZ;
    jx[r] = gi;
  }

  float acc[8];
  #pragma unroll
  for (int j = 0; j < 8; ++j) acc[j] = 0.0f;

  #pragma unroll
  for (int a = 0; a < 3; ++a) {
    #pragma unroll
    for (int b = 0; b < 3; ++b) {
      float w = wy[a] * wx[b];
      const uint4* cell = (const uint4*)(KGb + ((size_t)jy[a] * OSZ + jx[b]) * CC);
      uint4 v = cell[q];                      // 8 bf16 channels
      acc[0] = fmaf(w, __uint_as_float(v.x << 16),          acc[0]);
      acc[1] = fmaf(w, __uint_as_float(v.x & 0xffff0000u),  acc[1]);
      acc[2] = fmaf(w, __uint_as_float(v.y << 16),          acc[2]);
      acc[3] = fmaf(w, __uint_as_float(v.y & 0xffff0000u),  acc[3]);
      acc[4] = fmaf(w, __uint_as_float(v.z << 16),          acc[4]);
      acc[5] = fmaf(w, __uint_as_float(v.z & 0xffff0000u),  acc[5]);
      acc[6] = fmaf(w, __uint_as_float(v.w << 16),          acc[6]);
      acc[7] = fmaf(w, __uint_as_float(v.w & 0xffff0000u),  acc[7]);
    }
  }

  int c0 = q * 8;
  #pragma unroll
  for (int j = 0; j < 8; ++j) out[(size_t)(c0 + j) * PP + p] = acc[j];
}

extern "C" void kernel_launch(void* const* d_in, const int* in_sizes, int n_in,
                              void* d_out, int out_size, void* d_ws, size_t ws_size,
                              hipStream_t stream) {
  bool sizes_ok = (n_in >= 3) &&
                  (in_sizes[0] == CC * NN * NN) &&
                  (in_sizes[1] == CC * NN * NN) &&
                  (in_sizes[2] == PP * 2);
  if (!sizes_ok) {
    hipLaunchKernelGGL(sentinel_kernel, dim3(1), dim3(64), 0, stream,
                       (float*)d_out, 555.0f);
    return;
  }
  if (ws_size < (size_t)CC * OSZ * OSZ * sizeof(unsigned short)) {  // 4,147,200 B
    hipLaunchKernelGGL(sentinel_kernel, dim3(1), dim3(64), 0, stream,
                       (float*)d_out, 777.0f);
    return;
  }

  const float* imr   = (const float*)d_in[0];
  const float* imi   = (const float*)d_in[1];
  const float* coord = (const float*)d_in[2];

  // d_out = 4,194,304 float32 = 16.78 MB (real part of kdata, (C,P)).
  // T1h scratch (complex fp16, 8.29 MB) fits in d_out, dead before
  // grid_points2 overwrites all of d_out. KGb (bf16, 4.15 MB) in d_ws.
  __half2* T1h = (__half2*)d_out;
  unsigned short* KGb = (unsigned short*)d_ws;

  hipLaunchKernelGGL(nufft_pass1, dim3(CC * 180), dim3(192), 0, stream,
                     imr, imi, T1h);
  hipLaunchKernelGGL(nufft_pass2, dim3(OSZ * 8), dim3(192), 0, stream,
                     T1h, KGb);
  hipLaunchKernelGGL(grid_points2, dim3((PP * 2) / 256), dim3(256), 0, stream,
                     coord, KGb, (float*)d_out);
}